// Round 11
// baseline (41.759 us; speedup 1.0000x reference)
//
#include <hip/hip_runtime.h>

typedef _Float16 h4 __attribute__((ext_vector_type(4)));
typedef float f4 __attribute__((ext_vector_type(4)));
typedef _Float16 half_t;

#define WS_SXY   0
#define WS_W2H   32768
#define WS_W1H   49152
#define WS_WF1   51200
#define WS_WF2   69632
#define WS_WF3   86016
#define WS_HWS   102400

// ---------------- prep: pack sxy pairs + all MFMA operands to fragment-ordered fp16 ----------------
__global__ __launch_bounds__(256) void prep_kernel(
    const float* __restrict__ s,
    const float* __restrict__ w1, const float* __restrict__ b1,
    const float* __restrict__ w2, const float* __restrict__ fw1,
    const float* __restrict__ fw2, const float* __restrict__ fw3,
    float4* __restrict__ sxy2, h4* __restrict__ w2h, h4* __restrict__ w1h,
    h4* __restrict__ wf1h, h4* __restrict__ wf2h, h4* __restrict__ wf3h) {
  int tid = blockIdx.x*256 + threadIdx.x;
  if (tid < 2048) {                       // sxy2[p] = (x2p, y2p, x2p+1, y2p+1)
    float4 p0 = ((const float4*)s)[2*tid];
    float4 p1 = ((const float4*)s)[2*tid+1];
    float4 v; v.x = p0.x; v.y = p0.y; v.z = p1.x; v.w = p1.y;
    sxy2[tid] = v;
  } else if (tid < 4096) {                // edge w2 B-frags: K=64, N=128
    int idx = tid - 2048;
    int fl = idx & 63, ks = (idx>>6)&3, nt = idx>>8;
    int o = 16*nt + (fl&15), cb = 16*ks + 4*(fl>>4);
    const float* wr = w2 + o*64 + cb;
    h4 v; v[0]=(half_t)wr[0]; v[1]=(half_t)wr[1]; v[2]=(half_t)wr[2]; v[3]=(half_t)wr[3];
    w2h[idx] = v;
  } else if (tid < 4352) {                // edge w1 A-frags: M=64 (4 mtiles), K=16 (5 inputs + bias@k=5)
    int idx = tid - 4096;
    int fl = idx & 63, mt = idx >> 6;
    int o = 16*mt + (fl&15), k0 = 4*(fl>>4);
    h4 v;
#pragma unroll
    for (int q=0;q<4;++q) {
      int k = k0+q;
      float x = (k<5) ? w1[o*5+k] : (k==5 ? b1[o] : 0.0f);
      v[q] = (half_t)x;
    }
    w1h[idx] = v;
  } else if (tid < 6656) {                // fw1 B-frags: K=144(pad 132), N=64 -> 9 ktiles
    int idx = tid - 4352;
    int fl = idx & 63, rem = idx >> 6;    // 0..35
    int kt = rem % 9, nt = rem / 9;
    int n = 16*nt + (fl&15), k0 = 16*kt + 4*(fl>>4);
    h4 v;
#pragma unroll
    for (int q=0;q<4;++q) { int k = k0+q; v[q] = (k<132)?(half_t)fw1[n*132+k]:(half_t)0.f; }
    wf1h[idx] = v;
  } else if (tid < 8704) {                // fw2 B-frags: K=64, N=128
    int idx = tid - 6656;
    int fl = idx & 63, rem = idx >> 6;
    int kt = rem & 3, nt = rem >> 2;
    int n = 16*nt + (fl&15), k0 = 16*kt + 4*(fl>>4);
    h4 v;
#pragma unroll
    for (int q=0;q<4;++q) v[q] = (half_t)fw2[n*64 + k0 + q];
    wf2h[idx] = v;
  } else if (tid < 10752) {               // fw3 B-frags: K=128, N=64
    int idx = tid - 8704;
    int fl = idx & 63, rem = idx >> 6;
    int kt = rem & 7, nt = rem >> 3;
    int n = 16*nt + (fl&15), k0 = 16*kt + 4*(fl>>4);
    h4 v;
#pragma unroll
    for (int q=0;q<4;++q) v[q] = (half_t)fw3[n*128 + k0 + q];
    wf3h[idx] = v;
  }
}

// ---------------- kernel 1: 256 threads per row; key[16]/lane; restricted radix top-32 ----------------
#define CKT 0x05000000u   // key cap = float(0.5) bits - 0x3A000000

__global__ __launch_bounds__(256, 4) void neigh_kernel(
    const float* __restrict__ s, const float* __restrict__ b2,
    const float4* __restrict__ sxy2, const h4* __restrict__ w2h,
    const h4* __restrict__ w1h, half_t* __restrict__ hws) {
  __shared__ unsigned hist[2][512];   // reused post-scan: cand=hist[0][0..255], selq=(int*)hist[1][0..31]
  __shared__ unsigned wst[8];         // 2:selcnt 3:candcnt 4..7: per-wave near-count
  __shared__ float xk[32][8];         // features: dx,dy,dz,dw,eye,1.0,0,0
  __shared__ float maskv[32];

  const int t = threadIdx.x;
  const int w = t >> 6, l = t & 63;
  const int i = blockIdx.x;

  *(uint2*)&hist[0][2*t] = make_uint2(0,0);
  *(uint2*)&hist[1][2*t] = make_uint2(0,0);
  if (t < 8) wst[t] = 0;
  const float4 si = ((const float4*)s)[i];
  __syncthreads();  // B1: init done

  // ---- distance pass: 16 keys/lane in VGPRs (bitwise-IEEE); near-only histogram ----
  unsigned key[16];
  int ncl = 0;
#pragma unroll
  for (int ii = 0; ii < 8; ++ii) {
    float4 q = sxy2[t + (ii<<8)];
    float dx0 = __fsub_rn(si.x, q.x), dy0 = __fsub_rn(si.y, q.y);
    float a0 = __fadd_rn(__fmul_rn(dx0,dx0), 1e-6f);
    float b0 = __fadd_rn(__fmul_rn(dy0,dy0), 1e-6f);
    unsigned ck0 = __float_as_uint(__fsqrt_rn(__fadd_rn(a0,b0))) - 0x3A000000u;
    float dx1 = __fsub_rn(si.x, q.z), dy1 = __fsub_rn(si.y, q.w);
    float a1 = __fadd_rn(__fmul_rn(dx1,dx1), 1e-6f);
    float b1v = __fadd_rn(__fmul_rn(dy1,dy1), 1e-6f);
    unsigned ck1 = __float_as_uint(__fsqrt_rn(__fadd_rn(a1,b1v))) - 0x3A000000u;
    key[2*ii]   = ck0;
    key[2*ii+1] = ck1;
    if (ck0 < CKT) { ++ncl; atomicAdd(&hist[t&1][ck0>>18], 1u); }
    if (ck1 < CKT) { ++ncl; atomicAdd(&hist[t&1][ck1>>18], 1u); }
  }
#pragma unroll
  for (int off = 1; off < 64; off <<= 1) ncl += __shfl_xor(ncl, off, 64);
  if (l == 0) wst[4+w] = (unsigned)ncl;
  __syncthreads();  // B2: histogram + counts visible

  const unsigned ncl_total = wst[4]+wst[5]+wst[6]+wst[7];
  if (ncl_total < 32u) {    // rare fallback: add far items (uniform branch)
#pragma unroll
    for (int ii = 0; ii < 16; ++ii) {
      unsigned ck = key[ii];
      if (ck >= CKT) atomicAdd(&hist[t&1][min(ck>>18, 511u)], 1u);
    }
    __syncthreads();
  }

  // ---- scan 512 bins (redundant per wave, lane owns 8); (B,below) via max-reduce in regs ----
  unsigned B, below;
  {
    uint4 hA0 = *(uint4*)&hist[0][8*l], hA1 = *(uint4*)&hist[0][8*l+4];
    uint4 hB0 = *(uint4*)&hist[1][8*l], hB1 = *(uint4*)&hist[1][8*l+4];
    unsigned c[8] = {hA0.x+hB0.x, hA0.y+hB0.y, hA0.z+hB0.z, hA0.w+hB0.w,
                     hA1.x+hB1.x, hA1.y+hB1.y, hA1.z+hB1.z, hA1.w+hB1.w};
    unsigned p[8], run = 0;
#pragma unroll
    for (int q=0;q<8;++q) { run += c[q]; p[q] = run; }
    unsigned tot = run, v = tot;
#pragma unroll
    for (int off=1; off<64; off<<=1) {
      unsigned n = __shfl_up(v, off, 64);
      if (l >= off) v += n;
    }
    unsigned excl = v - tot;
    unsigned pack = 0;
    unsigned prev = excl;
#pragma unroll
    for (int q=0;q<8;++q) {
      unsigned cur = excl + p[q];
      if (prev < 32u && cur >= 32u) pack = ((8u*l+q) << 16) | prev;
      prev = cur;
    }
#pragma unroll
    for (int off=1; off<64; off<<=1) pack = max(pack, __shfl_xor(pack, off, 64));
    B = pack >> 16; below = pack & 0xFFFFu;
  }
  __syncthreads();  // B3: everyone done reading hist; safe to reuse as cand/selq

  unsigned* cand = &hist[0][0];
  int* selq = (int*)&hist[1][0];
  const unsigned long long ltm = (1ull << l) - 1ull;

  // ---- compaction: ballot-aggregated (1 atomic/wave/class/iter) ----
#pragma unroll
  for (int ii = 0; ii < 8; ++ii) {
    unsigned ck0 = key[2*ii], ck1 = key[2*ii+1];
    unsigned d0 = min(ck0>>18, 511u), d1 = min(ck1>>18, 511u);
    int j0 = 2*(t + (ii<<8)), j1 = j0 + 1;
    bool s0 = d0 < B, s1 = d1 < B, e0 = d0 == B, e1 = d1 == B;
    unsigned long long mS0 = __ballot(s0), mS1 = __ballot(s1);
    unsigned long long mE0 = __ballot(e0), mE1 = __ballot(e1);
    int nS = __popcll(mS0) + __popcll(mS1);
    int nE = __popcll(mE0) + __popcll(mE1);
    unsigned baseS = 0, baseE = 0;
    if (l == 0) {
      if (nS) baseS = atomicAdd(&wst[2], (unsigned)nS);
      if (nE) baseE = atomicAdd(&wst[3], (unsigned)nE);
    }
    baseS = __shfl(baseS, 0, 64);
    baseE = __shfl(baseE, 0, 64);
    if (s0) selq[baseS + __popcll(mS0 & ltm)] = j0;
    if (s1) selq[baseS + __popcll(mS0) + __popcll(mS1 & ltm)] = j1;
    if (e0) { unsigned p2 = baseE + __popcll(mE0 & ltm);
              if (p2 < 256u) cand[p2] = ((ck0 & 0x3FFFFu) << 12) | (unsigned)j0; }
    if (e1) { unsigned p2 = baseE + __popcll(mE0) + __popcll(mE1 & ltm);
              if (p2 < 256u) cand[p2] = ((ck1 & 0x3FFFFu) << 12) | (unsigned)j1; }
  }
  __syncthreads();  // B4: selq/cand complete

  // ---- extract (32-below) smallest by (key, idx): redundant on all waves (benign same-value writes) ----
  {
    int ncand = (int)wst[3];
    if (ncand > 256) ncand = 256;
    unsigned c0 = (l       < ncand) ? cand[l]     : 0xFFFFFFFFu;
    unsigned c1 = (l + 64  < ncand) ? cand[l+64]  : 0xFFFFFFFFu;
    unsigned c2 = (l + 128 < ncand) ? cand[l+128] : 0xFFFFFFFFu;
    unsigned c3 = (l + 192 < ncand) ? cand[l+192] : 0xFFFFFFFFu;
    int want = 32 - (int)below;
#pragma unroll 1
    for (int it=0; it<want; ++it) {
      unsigned mn = min(min(c0,c1), min(c2,c3));
#pragma unroll
      for (int off=1; off<64; off<<=1) mn = min(mn, __shfl_xor(mn, off, 64));
      c0 = (c0==mn)?0xFFFFFFFFu:c0;
      c1 = (c1==mn)?0xFFFFFFFFu:c1;
      c2 = (c2==mn)?0xFFFFFFFFu:c2;
      c3 = (c3==mn)?0xFFFFFFFFu:c3;
      if (l == 0) selq[(int)below + it] = (int)(mn & 0xFFFu);
    }
  }
  __builtin_amdgcn_wave_barrier();

  // ---- features + mask (wave0 lanes; own-wave selq writes already visible) ----
  if (t < 32) {
    int j = selq[t];
    float4 sj = ((const float4*)s)[j];
    float dx = __fsub_rn(si.x, sj.x);
    float dy = __fsub_rn(si.y, sj.y);
    xk[t][0] = dx; xk[t][1] = dy;
    xk[t][2] = __fsub_rn(si.z, sj.z);
    xk[t][3] = __fsub_rn(si.w, sj.w);
    xk[t][4] = (j == i) ? 1.0f : 0.0f;
    xk[t][5] = 1.0f;                  // bias channel for layer-1 MFMA
    xk[t][6] = 0.0f; xk[t][7] = 0.0f;
    float nn = __fsqrt_rn(__fadd_rn(__fmul_rn(dx,dx), __fmul_rn(dy,dy)));
    maskv[t] = (nn < 1.0f) ? 1.0f : 0.0f;
  }
  __syncthreads();  // B5: features ready

  const int lm = l & 15, lh = l >> 4;

  // ---- edge layer 1 (5->64) via MFMA (redundant per wave): D-frag == layer-2 A-frag ----
  h4 xb[2];
#pragma unroll
  for (int nt=0; nt<2; ++nt) {
    f4 xv = *(const f4*)&xk[16*nt + lm][4*lh];
    h4 b; b[0]=(half_t)xv[0]; b[1]=(half_t)xv[1]; b[2]=(half_t)xv[2]; b[3]=(half_t)xv[3];
    xb[nt] = b;
  }
  h4 af[2][4];
#pragma unroll
  for (int mt=0; mt<4; ++mt) {
    h4 wf = w1h[mt*64 + l];
    f4 d0 = {}, d1 = {};
    d0 = __builtin_amdgcn_mfma_f32_16x16x16f16(wf, xb[0], d0, 0,0,0);
    d1 = __builtin_amdgcn_mfma_f32_16x16x16f16(wf, xb[1], d1, 0,0,0);
#pragma unroll
    for (int q=0; q<4; ++q) {
      af[0][mt][q] = (half_t)fmaxf(d0[q], 0.0f);
      af[1][mt][q] = (half_t)fmaxf(d1[q], 0.0f);
    }
  }

  float pm[2][4];
#pragma unroll
  for (int mt=0; mt<2; ++mt)
#pragma unroll
    for (int jj=0; jj<4; ++jj) pm[mt][jj] = maskv[16*mt + 4*lh + jj];

  // ---- edge layer 2 (64->128): wave w handles n-tiles 2w, 2w+1 ----
#pragma unroll
  for (int u=0; u<2; ++u) {
    int nt = 2*w + u;
    h4 bf[4];
#pragma unroll
    for (int ks=0; ks<4; ++ks) bf[ks] = w2h[(nt*4+ks)*64 + l];
    f4 acc[2] = {};
#pragma unroll
    for (int ks=0; ks<4; ++ks) {
      acc[0] = __builtin_amdgcn_mfma_f32_16x16x16f16(af[0][ks], bf[ks], acc[0], 0,0,0);
      acc[1] = __builtin_amdgcn_mfma_f32_16x16x16f16(af[1][ks], bf[ks], acc[1], 0,0,0);
    }
    int o = 16*nt + lm;
    float bb = b2[o];
    float best = 0.0f;
#pragma unroll
    for (int mt=0; mt<2; ++mt)
#pragma unroll
      for (int jj=0; jj<4; ++jj)
        best = fmaxf(best, fmaxf(acc[mt][jj] + bb, 0.0f) * pm[mt][jj]);
    best = fmaxf(best, __shfl_xor(best, 16, 64));
    best = fmaxf(best, __shfl_xor(best, 32, 64));
    if (lh == 0) hws[i*128 + o] = (half_t)best;
  }
}

// ---------------- kernel 2: head MLP via MFMA, 16 rows/block ----------------
__global__ __launch_bounds__(256) void head_kernel(
    const float* __restrict__ s, const float* __restrict__ g,
    const h4* __restrict__ wf1h, const float* __restrict__ fb1,
    const h4* __restrict__ wf2h, const float* __restrict__ fb2,
    const h4* __restrict__ wf3h, const float* __restrict__ fb3,
    const float* __restrict__ fw4, const float* __restrict__ fb4,
    const half_t* __restrict__ hws, float* __restrict__ out) {
  const int t = threadIdx.x, base = blockIdx.x*16;
  const int w = t>>6, l = t&63, lm = l&15, lh = l>>4;
  __shared__ half_t a0[16][152];
  __shared__ half_t a1[16][68];
  __shared__ half_t a2[16][132];
  __shared__ float  a3[16][68];
  __shared__ float  kv[16][4];

  if (t < 128) {
    int r = t>>3, c0 = (t&7)*16;
    const uint4* src = (const uint4*)(hws + (base+r)*128 + c0);
    uint4 u0 = src[0], u1 = src[1];
    *(uint4*)&a0[r][c0] = u0;
    *(uint4*)&a0[r][c0+8] = u1;
  }
  if (t < 16) {
    float4 sv = ((const float4*)s)[base+t];
    float2 gv = ((const float2*)g)[base+t];
    a0[t][128] = (half_t)(sv.x - gv.x);
    a0[t][129] = (half_t)(sv.y - gv.y);
    a0[t][130] = (half_t)sv.z;
    a0[t][131] = (half_t)sv.w;
    *(uint2*)&a0[t][132] = make_uint2(0,0);
    *(uint4*)&a0[t][136] = make_uint4(0,0,0,0);
    *(uint4*)&a0[t][144] = make_uint4(0,0,0,0);
  }
  __syncthreads();

  // L1: [16x144]x[144x64]
  {
    h4 bf[9];
#pragma unroll
    for (int kt=0; kt<9; ++kt) bf[kt] = wf1h[(w*9 + kt)*64 + l];
    f4 acc = {};
#pragma unroll
    for (int kt=0; kt<9; ++kt) {
      h4 a = *(const h4*)&a0[lm][16*kt + 4*lh];
      acc = __builtin_amdgcn_mfma_f32_16x16x16f16(a, bf[kt], acc, 0,0,0);
    }
    int col = 16*w + lm;
    float bb = fb1[col];
#pragma unroll
    for (int jj=0;jj<4;++jj)
      a1[4*lh+jj][col] = (half_t)fmaxf(acc[jj] + bb, 0.0f);
  }
  __syncthreads();
  // L2: [16x64]x[64x128]
  {
    h4 bf[2][4];
#pragma unroll
    for (int u=0;u<2;++u) { int nt = 2*w+u;
#pragma unroll
      for (int kt=0;kt<4;++kt) bf[u][kt] = wf2h[(nt*4+kt)*64 + l]; }
    f4 acc[2] = {};
#pragma unroll
    for (int kt=0;kt<4;++kt) {
      h4 a = *(const h4*)&a1[lm][16*kt + 4*lh];
#pragma unroll
      for (int u=0;u<2;++u)
        acc[u] = __builtin_amdgcn_mfma_f32_16x16x16f16(a, bf[u][kt], acc[u], 0,0,0);
    }
#pragma unroll
    for (int u=0;u<2;++u) {
      int col = 16*(2*w+u) + lm;
      float bb = fb2[col];
#pragma unroll
      for (int jj=0;jj<4;++jj)
        a2[4*lh+jj][col] = (half_t)fmaxf(acc[u][jj] + bb, 0.0f);
    }
  }
  __syncthreads();
  // L3: [16x128]x[128x64]
  {
    h4 bf[8];
#pragma unroll
    for (int kt=0;kt<8;++kt) bf[kt] = wf3h[(w*8+kt)*64 + l];
    f4 acc = {};
#pragma unroll
    for (int kt=0;kt<8;++kt) {
      h4 a = *(const h4*)&a2[lm][16*kt + 4*lh];
      acc = __builtin_amdgcn_mfma_f32_16x16x16f16(a, bf[kt], acc, 0,0,0);
    }
    int col = 16*w + lm;
    float bb = fb3[col];
#pragma unroll
    for (int jj=0;jj<4;++jj)
      a3[4*lh+jj][col] = fmaxf(acc[jj] + bb, 0.0f);
  }
  __syncthreads();
  // L4: 64->4 fp32 + sigmoid gains
  if (t < 64) {
    int r = t>>2, oo = t&3;
    const f4* wrow = (const f4*)(fw4 + oo*64);
    const f4* arow = (const f4*)&a3[r][0];
    float acc = fb4[oo];
#pragma unroll
    for (int q=0;q<16;++q) {
      f4 a = arow[q], b = wrow[q];
      acc += a[0]*b[0] + a[1]*b[1] + a[2]*b[2] + a[3]*b[3];
    }
    kv[r][oo] = 2.0f / (1.0f + expf(-acc)) + 0.2f;
  }
  __syncthreads();
  if (t < 16) {
    int row = base + t;
    float4 sv = ((const float4*)s)[row];
    float2 gv = ((const float2*)g)[row];
    float st0 = sv.x - gv.x, st1 = sv.y - gv.y;
    out[row*2]   = -(kv[t][0]*st0 + kv[t][1]*sv.z);
    out[row*2+1] = -(kv[t][2]*st1 + kv[t][3]*sv.w);
  }
}

extern "C" void kernel_launch(void* const* d_in, const int* in_sizes, int n_in,
                              void* d_out, int out_size, void* d_ws, size_t ws_size,
                              hipStream_t stream) {
  const float* s   = (const float*)d_in[0];
  const float* g   = (const float*)d_in[1];
  const float* w1  = (const float*)d_in[2];
  const float* b1  = (const float*)d_in[3];
  const float* w2  = (const float*)d_in[4];
  const float* b2  = (const float*)d_in[5];
  const float* fw1 = (const float*)d_in[6];
  const float* fb1 = (const float*)d_in[7];
  const float* fw2 = (const float*)d_in[8];
  const float* fb2 = (const float*)d_in[9];
  const float* fw3 = (const float*)d_in[10];
  const float* fb3 = (const float*)d_in[11];
  const float* fw4 = (const float*)d_in[12];
  const float* fb4 = (const float*)d_in[13];
  float* out = (float*)d_out;
  char* ws = (char*)d_ws;
  float4* sxy2 = (float4*)(ws + WS_SXY);
  h4* w2h  = (h4*)(ws + WS_W2H);
  h4* w1h  = (h4*)(ws + WS_W1H);
  h4* wf1h = (h4*)(ws + WS_WF1);
  h4* wf2h = (h4*)(ws + WS_WF2);
  h4* wf3h = (h4*)(ws + WS_WF3);
  half_t* hws = (half_t*)(ws + WS_HWS);

  hipLaunchKernelGGL(prep_kernel, dim3(42), dim3(256), 0, stream,
                     s, w1, b1, w2, fw1, fw2, fw3, sxy2, w2h, w1h, wf1h, wf2h, wf3h);
  hipLaunchKernelGGL(neigh_kernel, dim3(4096), dim3(256), 0, stream,
                     s, b2, sxy2, w2h, w1h, hws);
  hipLaunchKernelGGL(head_kernel, dim3(256), dim3(256), 0, stream,
                     s, g, wf1h, fb1, wf2h, fb2, wf3h, fb3, fw4, fb4, hws, out);
}

// Round 12
// 39.323 us; speedup vs baseline: 1.0619x; 1.0619x over previous
//
#include <hip/hip_runtime.h>

typedef _Float16 h4 __attribute__((ext_vector_type(4)));
typedef float f4 __attribute__((ext_vector_type(4)));
typedef _Float16 half_t;

#define WS_SXY   0
#define WS_W2H   32768
#define WS_W1H   49152
#define WS_WF1   51200
#define WS_WF2   69632
#define WS_WF3   86016
#define WS_HWS   102400

// ---------------- prep: pack sxy pairs + all MFMA operands to fragment-ordered fp16 ----------------
__global__ __launch_bounds__(256) void prep_kernel(
    const float* __restrict__ s,
    const float* __restrict__ w1, const float* __restrict__ b1,
    const float* __restrict__ w2, const float* __restrict__ fw1,
    const float* __restrict__ fw2, const float* __restrict__ fw3,
    float4* __restrict__ sxy2, h4* __restrict__ w2h, h4* __restrict__ w1h,
    h4* __restrict__ wf1h, h4* __restrict__ wf2h, h4* __restrict__ wf3h) {
  int tid = blockIdx.x*256 + threadIdx.x;
  if (tid < 2048) {                       // sxy2[p] = (x2p, y2p, x2p+1, y2p+1)
    float4 p0 = ((const float4*)s)[2*tid];
    float4 p1 = ((const float4*)s)[2*tid+1];
    float4 v; v.x = p0.x; v.y = p0.y; v.z = p1.x; v.w = p1.y;
    sxy2[tid] = v;
  } else if (tid < 4096) {                // edge w2 B-frags: K=64, N=128
    int idx = tid - 2048;
    int fl = idx & 63, ks = (idx>>6)&3, nt = idx>>8;
    int o = 16*nt + (fl&15), cb = 16*ks + 4*(fl>>4);
    const float* wr = w2 + o*64 + cb;
    h4 v; v[0]=(half_t)wr[0]; v[1]=(half_t)wr[1]; v[2]=(half_t)wr[2]; v[3]=(half_t)wr[3];
    w2h[idx] = v;
  } else if (tid < 4352) {                // edge w1 A-frags: M=64 (4 mtiles), K=16 (5 inputs + bias@k=5)
    int idx = tid - 4096;
    int fl = idx & 63, mt = idx >> 6;
    int o = 16*mt + (fl&15), k0 = 4*(fl>>4);
    h4 v;
#pragma unroll
    for (int q=0;q<4;++q) {
      int k = k0+q;
      float x = (k<5) ? w1[o*5+k] : (k==5 ? b1[o] : 0.0f);
      v[q] = (half_t)x;
    }
    w1h[idx] = v;
  } else if (tid < 6656) {                // fw1 B-frags: K=144(pad 132), N=64 -> 9 ktiles
    int idx = tid - 4352;
    int fl = idx & 63, rem = idx >> 6;    // 0..35
    int kt = rem % 9, nt = rem / 9;
    int n = 16*nt + (fl&15), k0 = 16*kt + 4*(fl>>4);
    h4 v;
#pragma unroll
    for (int q=0;q<4;++q) { int k = k0+q; v[q] = (k<132)?(half_t)fw1[n*132+k]:(half_t)0.f; }
    wf1h[idx] = v;
  } else if (tid < 8704) {                // fw2 B-frags: K=64, N=128
    int idx = tid - 6656;
    int fl = idx & 63, rem = idx >> 6;
    int kt = rem & 3, nt = rem >> 2;
    int n = 16*nt + (fl&15), k0 = 16*kt + 4*(fl>>4);
    h4 v;
#pragma unroll
    for (int q=0;q<4;++q) v[q] = (half_t)fw2[n*64 + k0 + q];
    wf2h[idx] = v;
  } else if (tid < 10752) {               // fw3 B-frags: K=128, N=64
    int idx = tid - 8704;
    int fl = idx & 63, rem = idx >> 6;
    int kt = rem & 7, nt = rem >> 3;
    int n = 16*nt + (fl&15), k0 = 16*kt + 4*(fl>>4);
    h4 v;
#pragma unroll
    for (int q=0;q<4;++q) v[q] = (half_t)fw3[n*128 + k0 + q];
    wf3h[idx] = v;
  }
}

// ---------------- kernel 1: 256 threads per row; key[16]/lane; restricted radix top-32 ----------------
#define CKT 0x05000000u   // key cap = float(0.5) bits - 0x3A000000

__global__ __launch_bounds__(256, 6) void neigh_kernel(
    const float* __restrict__ s, const float* __restrict__ b2,
    const float4* __restrict__ sxy2, const h4* __restrict__ w2h,
    const h4* __restrict__ w1h, half_t* __restrict__ hws) {
  __shared__ unsigned hist[2][512];   // reused post-scan: cand=hist[0][0..255], selq=(int*)hist[1][0..31]
  __shared__ unsigned wst[8];         // 2:selcnt 3:candcnt 4..7: per-wave near-count
  __shared__ float xk[32][8];         // features: dx,dy,dz,dw,eye,1.0,0,0
  __shared__ float maskv[32];

  const int t = threadIdx.x;
  const int w = t >> 6, l = t & 63;
  const int i = blockIdx.x;

  *(uint2*)&hist[0][2*t] = make_uint2(0,0);
  *(uint2*)&hist[1][2*t] = make_uint2(0,0);
  if (t < 8) wst[t] = 0;
  const float4 si = ((const float4*)s)[i];
  __syncthreads();  // B1: init done

  // ---- distance pass: 16 keys/lane in VGPRs (bitwise-IEEE); near-only histogram ----
  unsigned key[16];
  int ncl = 0;
#pragma unroll
  for (int ii = 0; ii < 8; ++ii) {
    float4 q = sxy2[t + (ii<<8)];
    float dx0 = __fsub_rn(si.x, q.x), dy0 = __fsub_rn(si.y, q.y);
    float a0 = __fadd_rn(__fmul_rn(dx0,dx0), 1e-6f);
    float b0 = __fadd_rn(__fmul_rn(dy0,dy0), 1e-6f);
    unsigned ck0 = __float_as_uint(__fsqrt_rn(__fadd_rn(a0,b0))) - 0x3A000000u;
    float dx1 = __fsub_rn(si.x, q.z), dy1 = __fsub_rn(si.y, q.w);
    float a1 = __fadd_rn(__fmul_rn(dx1,dx1), 1e-6f);
    float b1v = __fadd_rn(__fmul_rn(dy1,dy1), 1e-6f);
    unsigned ck1 = __float_as_uint(__fsqrt_rn(__fadd_rn(a1,b1v))) - 0x3A000000u;
    key[2*ii]   = ck0;
    key[2*ii+1] = ck1;
    if (ck0 < CKT) { ++ncl; atomicAdd(&hist[t&1][ck0>>18], 1u); }
    if (ck1 < CKT) { ++ncl; atomicAdd(&hist[t&1][ck1>>18], 1u); }
  }
#pragma unroll
  for (int off = 1; off < 64; off <<= 1) ncl += __shfl_xor(ncl, off, 64);
  if (l == 0) wst[4+w] = (unsigned)ncl;
  __syncthreads();  // B2: histogram + counts visible

  const unsigned ncl_total = wst[4]+wst[5]+wst[6]+wst[7];
  if (ncl_total < 32u) {    // rare fallback: add far items (uniform branch)
#pragma unroll
    for (int ii = 0; ii < 16; ++ii) {
      unsigned ck = key[ii];
      if (ck >= CKT) atomicAdd(&hist[t&1][min(ck>>18, 511u)], 1u);
    }
    __syncthreads();
  }

  // ---- scan 512 bins (redundant per wave, lane owns 8); broadcast (B,below) via max-reduce ----
  unsigned B, below;
  {
    uint4 hA0 = *(uint4*)&hist[0][8*l], hA1 = *(uint4*)&hist[0][8*l+4];
    uint4 hB0 = *(uint4*)&hist[1][8*l], hB1 = *(uint4*)&hist[1][8*l+4];
    unsigned c[8] = {hA0.x+hB0.x, hA0.y+hB0.y, hA0.z+hB0.z, hA0.w+hB0.w,
                     hA1.x+hB1.x, hA1.y+hB1.y, hA1.z+hB1.z, hA1.w+hB1.w};
    unsigned p[8], run = 0;
#pragma unroll
    for (int q=0;q<8;++q) { run += c[q]; p[q] = run; }
    unsigned tot = run, v = tot;
#pragma unroll
    for (int off=1; off<64; off<<=1) {
      unsigned n = __shfl_up(v, off, 64);
      if (l >= off) v += n;
    }
    unsigned excl = v - tot;
    unsigned pack = 0;
    unsigned prev = excl;
#pragma unroll
    for (int q=0;q<8;++q) {
      unsigned cur = excl + p[q];
      if (prev < 32u && cur >= 32u) pack = ((8u*l+q) << 16) | prev;
      prev = cur;
    }
#pragma unroll
    for (int off=1; off<64; off<<=1) pack = max(pack, __shfl_xor(pack, off, 64));
    B = pack >> 16; below = pack & 0xFFFFu;
  }
  __syncthreads();  // B3: everyone done reading hist; safe to reuse as cand/selq

  unsigned* cand = &hist[0][0];
  int* selq = (int*)&hist[1][0];

  // ---- compact from registers: digit<B -> selected; digit==B -> boundary candidates ----
#pragma unroll
  for (int ii = 0; ii < 8; ++ii) {
    unsigned ck0 = key[2*ii], ck1 = key[2*ii+1];
    unsigned d0 = min(ck0>>18, 511u), d1 = min(ck1>>18, 511u);
    int j0 = 2*(t + (ii<<8)), j1 = j0 + 1;
    if (d0 < B)       { unsigned pos = atomicAdd(&wst[2], 1u); selq[pos] = j0; }
    else if (d0 == B) { unsigned pos = atomicAdd(&wst[3], 1u);
                        if (pos < 256u) cand[pos] = ((ck0 & 0x3FFFFu) << 12) | (unsigned)j0; }
    if (d1 < B)       { unsigned pos = atomicAdd(&wst[2], 1u); selq[pos] = j1; }
    else if (d1 == B) { unsigned pos = atomicAdd(&wst[3], 1u);
                        if (pos < 256u) cand[pos] = ((ck1 & 0x3FFFFu) << 12) | (unsigned)j1; }
  }
  __syncthreads();  // B4: selq/cand complete

  // ---- extract (32-below) smallest by (key, idx) on wave 0: exact reference tie-break ----
  if (w == 0) {
    int ncand = (int)wst[3];
    if (ncand > 256) ncand = 256;
    unsigned c0 = (l       < ncand) ? cand[l]     : 0xFFFFFFFFu;
    unsigned c1 = (l + 64  < ncand) ? cand[l+64]  : 0xFFFFFFFFu;
    unsigned c2 = (l + 128 < ncand) ? cand[l+128] : 0xFFFFFFFFu;
    unsigned c3 = (l + 192 < ncand) ? cand[l+192] : 0xFFFFFFFFu;
    int want = 32 - (int)below;
#pragma unroll 1
    for (int it=0; it<want; ++it) {
      unsigned mn = min(min(c0,c1), min(c2,c3));
#pragma unroll
      for (int off=1; off<64; off<<=1) mn = min(mn, __shfl_xor(mn, off, 64));
      c0 = (c0==mn)?0xFFFFFFFFu:c0;
      c1 = (c1==mn)?0xFFFFFFFFu:c1;
      c2 = (c2==mn)?0xFFFFFFFFu:c2;
      c3 = (c3==mn)?0xFFFFFFFFu:c3;
      if (l == 0) selq[(int)below + it] = (int)(mn & 0xFFFu);
    }
  }
  __syncthreads();  // B5: selq complete

  // ---- features + mask ----
  if (t < 32) {
    int j = selq[t];
    float4 sj = ((const float4*)s)[j];
    float dx = __fsub_rn(si.x, sj.x);
    float dy = __fsub_rn(si.y, sj.y);
    xk[t][0] = dx; xk[t][1] = dy;
    xk[t][2] = __fsub_rn(si.z, sj.z);
    xk[t][3] = __fsub_rn(si.w, sj.w);
    xk[t][4] = (j == i) ? 1.0f : 0.0f;
    xk[t][5] = 1.0f;                  // bias channel for layer-1 MFMA
    xk[t][6] = 0.0f; xk[t][7] = 0.0f;
    float nn = __fsqrt_rn(__fadd_rn(__fmul_rn(dx,dx), __fmul_rn(dy,dy)));
    maskv[t] = (nn < 1.0f) ? 1.0f : 0.0f;
  }
  __syncthreads();  // B6: features ready

  const int lm = l & 15, lh = l >> 4;

  // ---- edge layer 1 (5->64) via MFMA (redundant per wave): D-frag == layer-2 A-frag ----
  h4 xb[2];
#pragma unroll
  for (int nt=0; nt<2; ++nt) {
    f4 xv = *(const f4*)&xk[16*nt + lm][4*lh];
    h4 b; b[0]=(half_t)xv[0]; b[1]=(half_t)xv[1]; b[2]=(half_t)xv[2]; b[3]=(half_t)xv[3];
    xb[nt] = b;
  }
  h4 af[2][4];
#pragma unroll
  for (int mt=0; mt<4; ++mt) {
    h4 wf = w1h[mt*64 + l];
    f4 d0 = {}, d1 = {};
    d0 = __builtin_amdgcn_mfma_f32_16x16x16f16(wf, xb[0], d0, 0,0,0);
    d1 = __builtin_amdgcn_mfma_f32_16x16x16f16(wf, xb[1], d1, 0,0,0);
#pragma unroll
    for (int q=0; q<4; ++q) {
      af[0][mt][q] = (half_t)fmaxf(d0[q], 0.0f);
      af[1][mt][q] = (half_t)fmaxf(d1[q], 0.0f);
    }
  }

  float pm[2][4];
#pragma unroll
  for (int mt=0; mt<2; ++mt)
#pragma unroll
    for (int jj=0; jj<4; ++jj) pm[mt][jj] = maskv[16*mt + 4*lh + jj];

  // ---- edge layer 2 (64->128): wave w handles n-tiles 2w, 2w+1 ----
#pragma unroll
  for (int u=0; u<2; ++u) {
    int nt = 2*w + u;
    h4 bf[4];
#pragma unroll
    for (int ks=0; ks<4; ++ks) bf[ks] = w2h[(nt*4+ks)*64 + l];
    f4 acc[2] = {};
#pragma unroll
    for (int ks=0; ks<4; ++ks) {
      acc[0] = __builtin_amdgcn_mfma_f32_16x16x16f16(af[0][ks], bf[ks], acc[0], 0,0,0);
      acc[1] = __builtin_amdgcn_mfma_f32_16x16x16f16(af[1][ks], bf[ks], acc[1], 0,0,0);
    }
    int o = 16*nt + lm;
    float bb = b2[o];
    float best = 0.0f;
#pragma unroll
    for (int mt=0; mt<2; ++mt)
#pragma unroll
      for (int jj=0; jj<4; ++jj)
        best = fmaxf(best, fmaxf(acc[mt][jj] + bb, 0.0f) * pm[mt][jj]);
    best = fmaxf(best, __shfl_xor(best, 16, 64));
    best = fmaxf(best, __shfl_xor(best, 32, 64));
    if (lh == 0) hws[i*128 + o] = (half_t)best;
  }
}

// ---------------- kernel 2: head MLP via MFMA, 16 rows/block ----------------
__global__ __launch_bounds__(256) void head_kernel(
    const float* __restrict__ s, const float* __restrict__ g,
    const h4* __restrict__ wf1h, const float* __restrict__ fb1,
    const h4* __restrict__ wf2h, const float* __restrict__ fb2,
    const h4* __restrict__ wf3h, const float* __restrict__ fb3,
    const float* __restrict__ fw4, const float* __restrict__ fb4,
    const half_t* __restrict__ hws, float* __restrict__ out) {
  const int t = threadIdx.x, base = blockIdx.x*16;
  const int w = t>>6, l = t&63, lm = l&15, lh = l>>4;
  __shared__ half_t a0[16][152];
  __shared__ half_t a1[16][68];
  __shared__ half_t a2[16][132];
  __shared__ float  a3[16][68];
  __shared__ float  kv[16][4];

  if (t < 128) {
    int r = t>>3, c0 = (t&7)*16;
    const uint4* src = (const uint4*)(hws + (base+r)*128 + c0);
    uint4 u0 = src[0], u1 = src[1];
    *(uint4*)&a0[r][c0] = u0;
    *(uint4*)&a0[r][c0+8] = u1;
  }
  if (t < 16) {
    float4 sv = ((const float4*)s)[base+t];
    float2 gv = ((const float2*)g)[base+t];
    a0[t][128] = (half_t)(sv.x - gv.x);
    a0[t][129] = (half_t)(sv.y - gv.y);
    a0[t][130] = (half_t)sv.z;
    a0[t][131] = (half_t)sv.w;
    *(uint2*)&a0[t][132] = make_uint2(0,0);
    *(uint4*)&a0[t][136] = make_uint4(0,0,0,0);
    *(uint4*)&a0[t][144] = make_uint4(0,0,0,0);
  }
  __syncthreads();

  // L1: [16x144]x[144x64]
  {
    h4 bf[9];
#pragma unroll
    for (int kt=0; kt<9; ++kt) bf[kt] = wf1h[(w*9 + kt)*64 + l];
    f4 acc = {};
#pragma unroll
    for (int kt=0; kt<9; ++kt) {
      h4 a = *(const h4*)&a0[lm][16*kt + 4*lh];
      acc = __builtin_amdgcn_mfma_f32_16x16x16f16(a, bf[kt], acc, 0,0,0);
    }
    int col = 16*w + lm;
    float bb = fb1[col];
#pragma unroll
    for (int jj=0;jj<4;++jj)
      a1[4*lh+jj][col] = (half_t)fmaxf(acc[jj] + bb, 0.0f);
  }
  __syncthreads();
  // L2: [16x64]x[64x128]
  {
    h4 bf[2][4];
#pragma unroll
    for (int u=0;u<2;++u) { int nt = 2*w+u;
#pragma unroll
      for (int kt=0;kt<4;++kt) bf[u][kt] = wf2h[(nt*4+kt)*64 + l]; }
    f4 acc[2] = {};
#pragma unroll
    for (int kt=0;kt<4;++kt) {
      h4 a = *(const h4*)&a1[lm][16*kt + 4*lh];
#pragma unroll
      for (int u=0;u<2;++u)
        acc[u] = __builtin_amdgcn_mfma_f32_16x16x16f16(a, bf[u][kt], acc[u], 0,0,0);
    }
#pragma unroll
    for (int u=0;u<2;++u) {
      int col = 16*(2*w+u) + lm;
      float bb = fb2[col];
#pragma unroll
      for (int jj=0;jj<4;++jj)
        a2[4*lh+jj][col] = (half_t)fmaxf(acc[u][jj] + bb, 0.0f);
    }
  }
  __syncthreads();
  // L3: [16x128]x[128x64]
  {
    h4 bf[8];
#pragma unroll
    for (int kt=0;kt<8;++kt) bf[kt] = wf3h[(w*8+kt)*64 + l];
    f4 acc = {};
#pragma unroll
    for (int kt=0;kt<8;++kt) {
      h4 a = *(const h4*)&a2[lm][16*kt + 4*lh];
      acc = __builtin_amdgcn_mfma_f32_16x16x16f16(a, bf[kt], acc, 0,0,0);
    }
    int col = 16*w + lm;
    float bb = fb3[col];
#pragma unroll
    for (int jj=0;jj<4;++jj)
      a3[4*lh+jj][col] = fmaxf(acc[jj] + bb, 0.0f);
  }
  __syncthreads();
  // L4: 64->4 fp32 + sigmoid gains
  if (t < 64) {
    int r = t>>2, oo = t&3;
    const f4* wrow = (const f4*)(fw4 + oo*64);
    const f4* arow = (const f4*)&a3[r][0];
    float acc = fb4[oo];
#pragma unroll
    for (int q=0;q<16;++q) {
      f4 a = arow[q], b = wrow[q];
      acc += a[0]*b[0] + a[1]*b[1] + a[2]*b[2] + a[3]*b[3];
    }
    kv[r][oo] = 2.0f / (1.0f + expf(-acc)) + 0.2f;
  }
  __syncthreads();
  if (t < 16) {
    int row = base + t;
    float4 sv = ((const float4*)s)[row];
    float2 gv = ((const float2*)g)[row];
    float st0 = sv.x - gv.x, st1 = sv.y - gv.y;
    out[row*2]   = -(kv[t][0]*st0 + kv[t][1]*sv.z);
    out[row*2+1] = -(kv[t][2]*st1 + kv[t][3]*sv.w);
  }
}

extern "C" void kernel_launch(void* const* d_in, const int* in_sizes, int n_in,
                              void* d_out, int out_size, void* d_ws, size_t ws_size,
                              hipStream_t stream) {
  const float* s   = (const float*)d_in[0];
  const float* g   = (const float*)d_in[1];
  const float* w1  = (const float*)d_in[2];
  const float* b1  = (const float*)d_in[3];
  const float* w2  = (const float*)d_in[4];
  const float* b2  = (const float*)d_in[5];
  const float* fw1 = (const float*)d_in[6];
  const float* fb1 = (const float*)d_in[7];
  const float* fw2 = (const float*)d_in[8];
  const float* fb2 = (const float*)d_in[9];
  const float* fw3 = (const float*)d_in[10];
  const float* fb3 = (const float*)d_in[11];
  const float* fw4 = (const float*)d_in[12];
  const float* fb4 = (const float*)d_in[13];
  float* out = (float*)d_out;
  char* ws = (char*)d_ws;
  float4* sxy2 = (float4*)(ws + WS_SXY);
  h4* w2h  = (h4*)(ws + WS_W2H);
  h4* w1h  = (h4*)(ws + WS_W1H);
  h4* wf1h = (h4*)(ws + WS_WF1);
  h4* wf2h = (h4*)(ws + WS_WF2);
  h4* wf3h = (h4*)(ws + WS_WF3);
  half_t* hws = (half_t*)(ws + WS_HWS);

  hipLaunchKernelGGL(prep_kernel, dim3(42), dim3(256), 0, stream,
                     s, w1, b1, w2, fw1, fw2, fw3, sxy2, w2h, w1h, wf1h, wf2h, wf3h);
  hipLaunchKernelGGL(neigh_kernel, dim3(4096), dim3(256), 0, stream,
                     s, b2, sxy2, w2h, w1h, hws);
  hipLaunchKernelGGL(head_kernel, dim3(256), dim3(256), 0, stream,
                     s, g, wf1h, fb1, wf2h, fb2, wf3h, fb3, fw4, fb4, hws, out);
}